// Round 1
// baseline (839.031 us; speedup 1.0000x reference)
//
#include <hip/hip_runtime.h>
#include <hip/hip_bf16.h>

// Glm4MoeExpertLayers: x[T,H] fp32, Wgu[E,2I,H] fp32, Wdn[E,H,I] fp32, expert_idx
//   gu = x @ Wgu[e]^T ; hidden = silu(gu[:, :I]) * gu[:, I:] ; out = hidden @ Wdn[e]^T
// T=16384 H=2048 I=1536. bf16 MFMA path, fp32 accumulate.

namespace {

constexpr int T_ = 16384;
constexpr int H_ = 2048;
constexpr int I_ = 1536;

typedef short short8 __attribute__((ext_vector_type(8)));
typedef float f32x4 __attribute__((ext_vector_type(4)));
typedef unsigned short ushort4v __attribute__((ext_vector_type(4)));

// fp32 -> bf16 round-to-nearest-even
__device__ __forceinline__ unsigned short f2bf(float f) {
    union { float f; unsigned u; } v; v.f = f;
    return (unsigned short)((v.u + 0x7FFFu + ((v.u >> 16) & 1u)) >> 16);
}

// byte offset into a [128 rows][64 bf16 cols] LDS tile, XOR-swizzled (T2).
// Applied identically on write and read sides (reg-staged, so both sides free).
__device__ __forceinline__ int swz(int r, int byteoff) {
    return (r * 128 + byteoff) ^ ((r & 7) << 4);
}

// ---------------------------------------------------------------------------
// GEMM1 + SwiGLU: hidden[T,I] (bf16) = silu(x@Wg^T) * (x@Wu^T)
// Block: 256 thr (4 waves, 2x2), tile 128(M) x 128(N), dual-B (gate row n,
// up row I+n of Wgu). BK=64, K loop over H=2048.
// ---------------------------------------------------------------------------
__global__ __launch_bounds__(256, 2) void k_gemm1_swiglu(
    const float* __restrict__ x, const float* __restrict__ wgu_all,
    const int* __restrict__ eidx, unsigned short* __restrict__ hidden)
{
    const float* wgu = wgu_all + (size_t)(*eidx) * (size_t)(2 * I_) * H_;

    __shared__ unsigned short lds[3 * 128 * 64];
    unsigned short* ldsA  = lds;
    unsigned short* ldsBg = lds + 128 * 64;
    unsigned short* ldsBu = lds + 2 * 128 * 64;

    const int tid  = threadIdx.x;
    const int lane = tid & 63;
    const int wv   = tid >> 6;
    const int wr   = wv >> 1, wc = wv & 1;
    const int m0   = blockIdx.y * 128;
    const int n0   = blockIdx.x * 128;

    f32x4 accG[4][4], accU[4][4];
    #pragma unroll
    for (int a = 0; a < 4; ++a)
        #pragma unroll
        for (int b = 0; b < 4; ++b) { accG[a][b] = (f32x4)0.0f; accU[a][b] = (f32x4)0.0f; }

    const int sr = tid >> 4;            // staging row base 0..15
    const int sc = (tid & 15) * 4;      // staging col (elements)
    const int l15 = lane & 15;
    const int l4  = lane >> 4;

    for (int k0 = 0; k0 < H_; k0 += 64) {
        __syncthreads();
        // stage A / Bgate / Bup : fp32 -> bf16 -> LDS (swizzled)
        #pragma unroll
        for (int i = 0; i < 8; ++i) {
            const int r = i * 16 + sr;
            f32x4 vA = *(const f32x4*)(x   + (size_t)(m0 + r)      * H_ + k0 + sc);
            f32x4 vG = *(const f32x4*)(wgu + (size_t)(n0 + r)      * H_ + k0 + sc);
            f32x4 vU = *(const f32x4*)(wgu + (size_t)(I_ + n0 + r) * H_ + k0 + sc);
            ushort4v hA = { f2bf(vA[0]), f2bf(vA[1]), f2bf(vA[2]), f2bf(vA[3]) };
            ushort4v hG = { f2bf(vG[0]), f2bf(vG[1]), f2bf(vG[2]), f2bf(vG[3]) };
            ushort4v hU = { f2bf(vU[0]), f2bf(vU[1]), f2bf(vU[2]), f2bf(vU[3]) };
            const int off = swz(r, sc * 2);
            *(ushort4v*)((char*)ldsA  + off) = hA;
            *(ushort4v*)((char*)ldsBg + off) = hG;
            *(ushort4v*)((char*)ldsBu + off) = hU;
        }
        __syncthreads();

        #pragma unroll
        for (int kk = 0; kk < 2; ++kk) {
            short8 af[4], bg[4], bu[4];
            #pragma unroll
            for (int a = 0; a < 4; ++a) {
                const int r = wr * 64 + a * 16 + l15;
                af[a] = *(const short8*)((const char*)ldsA + swz(r, kk * 64 + l4 * 16));
            }
            #pragma unroll
            for (int b = 0; b < 4; ++b) {
                const int r = wc * 64 + b * 16 + l15;
                const int off = swz(r, kk * 64 + l4 * 16);
                bg[b] = *(const short8*)((const char*)ldsBg + off);
                bu[b] = *(const short8*)((const char*)ldsBu + off);
            }
            #pragma unroll
            for (int a = 0; a < 4; ++a)
                #pragma unroll
                for (int b = 0; b < 4; ++b) {
                    accG[a][b] = __builtin_amdgcn_mfma_f32_16x16x32_bf16(af[a], bg[b], accG[a][b], 0, 0, 0);
                    accU[a][b] = __builtin_amdgcn_mfma_f32_16x16x32_bf16(af[a], bu[b], accU[a][b], 0, 0, 0);
                }
        }
    }

    // epilogue: silu(gate)*up -> bf16 hidden
    #pragma unroll
    for (int a = 0; a < 4; ++a)
        #pragma unroll
        for (int b = 0; b < 4; ++b)
            #pragma unroll
            for (int j = 0; j < 4; ++j) {
                const int row = m0 + wr * 64 + a * 16 + l4 * 4 + j;
                const int col = n0 + wc * 64 + b * 16 + l15;
                const float g = accG[a][b][j];
                const float u = accU[a][b][j];
                const float s = g / (1.0f + __expf(-g));
                hidden[(size_t)row * I_ + col] = f2bf(s * u);
            }
}

// ---------------------------------------------------------------------------
// GEMM2: out[T,H] fp32 = hidden(bf16) @ Wdn[e]^T.  K loop over I=1536.
// ---------------------------------------------------------------------------
__global__ __launch_bounds__(256, 2) void k_gemm2(
    const unsigned short* __restrict__ hidden, const float* __restrict__ wdn_all,
    const int* __restrict__ eidx, float* __restrict__ out)
{
    const float* wdn = wdn_all + (size_t)(*eidx) * (size_t)H_ * I_;

    __shared__ unsigned short lds[2 * 128 * 64];
    unsigned short* ldsA = lds;
    unsigned short* ldsB = lds + 128 * 64;

    const int tid  = threadIdx.x;
    const int lane = tid & 63;
    const int wv   = tid >> 6;
    const int wr   = wv >> 1, wc = wv & 1;
    const int m0   = blockIdx.y * 128;
    const int n0   = blockIdx.x * 128;

    f32x4 acc[4][4];
    #pragma unroll
    for (int a = 0; a < 4; ++a)
        #pragma unroll
        for (int b = 0; b < 4; ++b) acc[a][b] = (f32x4)0.0f;

    const int sr = tid >> 4;
    const int sc = (tid & 15) * 4;
    const int l15 = lane & 15;
    const int l4  = lane >> 4;

    for (int k0 = 0; k0 < I_; k0 += 64) {
        __syncthreads();
        // stage A: bf16 direct, 16B chunks
        #pragma unroll
        for (int i = 0; i < 4; ++i) {
            const int chunk = i * 256 + tid;
            const int r  = chunk >> 3;
            const int c8 = chunk & 7;
            short8 v = *(const short8*)(hidden + (size_t)(m0 + r) * I_ + k0 + c8 * 8);
            *(short8*)((char*)ldsA + swz(r, c8 * 16)) = v;
        }
        // stage B: fp32 -> bf16
        #pragma unroll
        for (int i = 0; i < 8; ++i) {
            const int r = i * 16 + sr;
            f32x4 vB = *(const f32x4*)(wdn + (size_t)(n0 + r) * I_ + k0 + sc);
            ushort4v hB = { f2bf(vB[0]), f2bf(vB[1]), f2bf(vB[2]), f2bf(vB[3]) };
            *(ushort4v*)((char*)ldsB + swz(r, sc * 2)) = hB;
        }
        __syncthreads();

        #pragma unroll
        for (int kk = 0; kk < 2; ++kk) {
            short8 af[4], bw[4];
            #pragma unroll
            for (int a = 0; a < 4; ++a) {
                const int r = wr * 64 + a * 16 + l15;
                af[a] = *(const short8*)((const char*)ldsA + swz(r, kk * 64 + l4 * 16));
            }
            #pragma unroll
            for (int b = 0; b < 4; ++b) {
                const int r = wc * 64 + b * 16 + l15;
                bw[b] = *(const short8*)((const char*)ldsB + swz(r, kk * 64 + l4 * 16));
            }
            #pragma unroll
            for (int a = 0; a < 4; ++a)
                #pragma unroll
                for (int b = 0; b < 4; ++b)
                    acc[a][b] = __builtin_amdgcn_mfma_f32_16x16x32_bf16(af[a], bw[b], acc[a][b], 0, 0, 0);
        }
    }

    #pragma unroll
    for (int a = 0; a < 4; ++a)
        #pragma unroll
        for (int b = 0; b < 4; ++b)
            #pragma unroll
            for (int j = 0; j < 4; ++j) {
                const int row = m0 + wr * 64 + a * 16 + l4 * 4 + j;
                const int col = n0 + wc * 64 + b * 16 + l15;
                out[(size_t)row * H_ + col] = acc[a][b][j];
            }
}

} // namespace

extern "C" void kernel_launch(void* const* d_in, const int* in_sizes, int n_in,
                              void* d_out, int out_size, void* d_ws, size_t ws_size,
                              hipStream_t stream) {
    const float* x   = (const float*)d_in[0];   // [T, H]
    const float* wgu = (const float*)d_in[1];   // [E, 2I, H]
    const float* wdn = (const float*)d_in[2];   // [E, H, I]
    const int* eidx  = (const int*)d_in[3];     // [1]
    float* out = (float*)d_out;                 // [T, H]
    unsigned short* hidden = (unsigned short*)d_ws; // [T, I] bf16 (50.3 MB)

    k_gemm1_swiglu<<<dim3(I_ / 128, T_ / 128), 256, 0, stream>>>(x, wgu, eidx, hidden);
    k_gemm2<<<dim3(H_ / 128, T_ / 128), 256, 0, stream>>>(hidden, wdn, eidx, out);
}

// Round 2
// 407.564 us; speedup vs baseline: 2.0586x; 2.0586x over previous
//
#include <hip/hip_runtime.h>
#include <hip/hip_bf16.h>

// Glm4MoeExpertLayers: x[T,H] fp32, Wgu[E,2I,H] fp32, Wdn[E,H,I] fp32, expert_idx
//   gu = x @ Wgu[e]^T ; hidden = silu(gu[:, :I]) * gu[:, I:] ; out = hidden @ Wdn[e]^T
// T=16384 H=2048 I=1536.
// R2: pre-convert weights to bf16 in ws; global_load_lds (width 16) staging for
// all-bf16 operands; A (fp32 x) reg-staged + swizzled in GEMM1; XCD block swizzle.

namespace {

constexpr int T_ = 16384;
constexpr int H_ = 2048;
constexpr int I_ = 1536;

typedef short short8 __attribute__((ext_vector_type(8)));
typedef float f32x4 __attribute__((ext_vector_type(4)));
typedef unsigned short ushort4v __attribute__((ext_vector_type(4)));

// fp32 -> bf16 round-to-nearest-even
__device__ __forceinline__ unsigned short f2bf(float f) {
    union { float f; unsigned u; } v; v.f = f;
    return (unsigned short)((v.u + 0x7FFFu + ((v.u >> 16) & 1u)) >> 16);
}

// byte offset into a [128 rows][64 bf16] LDS tile, XOR-swizzled (T2).
// Used ONLY for reg-staged tiles (write and read both swizzled).
__device__ __forceinline__ int swz(int r, int byteoff) {
    return (r * 128 + byteoff) ^ ((r & 7) << 4);
}

// async global->LDS, 16B per lane. LDS dest must be wave-uniform base (+lane*16 by HW).
typedef __attribute__((address_space(1))) const void gvoid;
typedef __attribute__((address_space(3))) void lvoid;
__device__ __forceinline__ void gload16(const void* g, void* l) {
    __builtin_amdgcn_global_load_lds((gvoid*)g, (lvoid*)l, 16, 0, 0);
}

// ---------------------------------------------------------------------------
// fp32 -> bf16 conversion (weights). src = base + (*eidx)*sliceElems.
// ---------------------------------------------------------------------------
__global__ void k_cvt(const float* __restrict__ base, const int* __restrict__ eidx,
                      long sliceElems, unsigned short* __restrict__ dst, int n4) {
    const float* src = base + (size_t)(*eidx) * (size_t)sliceElems;
    int i = blockIdx.x * blockDim.x + threadIdx.x;
    const int stride = gridDim.x * blockDim.x;
    for (; i < n4; i += stride) {
        f32x4 v = ((const f32x4*)src)[i];
        ushort4v h = { f2bf(v[0]), f2bf(v[1]), f2bf(v[2]), f2bf(v[3]) };
        ((ushort4v*)dst)[i] = h;
    }
}

// ---------------------------------------------------------------------------
// GEMM1 + SwiGLU: hidden[T,I](bf16) = silu(x@Wg^T) * (x@Wu^T)
// 256 thr (4 waves 2x2), tile 128x128, BK=64 over H.
// A: fp32 x, reg-staged -> bf16 -> swizzled LDS.
// Bg/Bu: bf16 weights, global_load_lds -> linear LDS.
// ---------------------------------------------------------------------------
__global__ __launch_bounds__(256, 2) void k_gemm1_swiglu(
    const float* __restrict__ x, const unsigned short* __restrict__ wgub,
    unsigned short* __restrict__ hidden)
{
    __shared__ unsigned short lds[3 * 128 * 64];
    unsigned short* ldsA  = lds;                 // swizzled
    unsigned short* ldsBg = lds + 128 * 64;      // linear [128][64]
    unsigned short* ldsBu = lds + 2 * 128 * 64;  // linear

    const int tid  = threadIdx.x;
    const int lane = tid & 63;
    const int wv   = tid >> 6;
    const int wr   = wv >> 1, wc = wv & 1;

    // XCD-aware bijective swizzle over 1536 blocks (1536 % 8 == 0)
    const int nb = (blockIdx.x & 7) * 192 + (blockIdx.x >> 3);
    const int bx = nb % 12, by = nb / 12;
    const int m0 = by * 128;
    const int n0 = bx * 128;

    f32x4 accG[4][4], accU[4][4];
    #pragma unroll
    for (int a = 0; a < 4; ++a)
        #pragma unroll
        for (int b = 0; b < 4; ++b) { accG[a][b] = (f32x4)0.0f; accU[a][b] = (f32x4)0.0f; }

    // DMA staging coords: 1KB per wave-issue = 8 rows of 128B
    const int drow = lane >> 3;          // 0..7
    const int dcol = (lane & 7) * 8;     // bf16 elem col
    // A reg-staging coords
    const int sr = tid >> 4;             // 0..15
    const int sc = (tid & 15) * 4;       // fp32 elem col
    const int l15 = lane & 15;
    const int l4  = lane >> 4;

    for (int k0 = 0; k0 < H_; k0 += 64) {
        __syncthreads();
        // issue B DMA first (8 in flight), then A loads overlap
        #pragma unroll
        for (int r = 0; r < 4; ++r) {
            const int row = r * 32 + wv * 8 + drow;
            const int loff = r * 2048 + wv * 512;   // ushort units, wave-uniform
            gload16(wgub + (size_t)(n0 + row)       * H_ + k0 + dcol, ldsBg + loff);
            gload16(wgub + (size_t)(I_ + n0 + row)  * H_ + k0 + dcol, ldsBu + loff);
        }
        #pragma unroll
        for (int i = 0; i < 8; ++i) {
            const int r = i * 16 + sr;
            f32x4 vA = *(const f32x4*)(x + (size_t)(m0 + r) * H_ + k0 + sc);
            ushort4v hA = { f2bf(vA[0]), f2bf(vA[1]), f2bf(vA[2]), f2bf(vA[3]) };
            *(ushort4v*)((char*)ldsA + swz(r, sc * 2)) = hA;
        }
        __syncthreads();

        #pragma unroll
        for (int kk = 0; kk < 2; ++kk) {
            short8 af[4], bg[4], bu[4];
            #pragma unroll
            for (int a = 0; a < 4; ++a) {
                const int r = wr * 64 + a * 16 + l15;
                af[a] = *(const short8*)((const char*)ldsA + swz(r, kk * 64 + l4 * 16));
            }
            #pragma unroll
            for (int b = 0; b < 4; ++b) {
                const int r = wc * 64 + b * 16 + l15;
                bg[b] = *(const short8*)(ldsBg + r * 64 + kk * 32 + l4 * 8);
                bu[b] = *(const short8*)(ldsBu + r * 64 + kk * 32 + l4 * 8);
            }
            #pragma unroll
            for (int a = 0; a < 4; ++a)
                #pragma unroll
                for (int b = 0; b < 4; ++b) {
                    accG[a][b] = __builtin_amdgcn_mfma_f32_16x16x32_bf16(af[a], bg[b], accG[a][b], 0, 0, 0);
                    accU[a][b] = __builtin_amdgcn_mfma_f32_16x16x32_bf16(af[a], bu[b], accU[a][b], 0, 0, 0);
                }
        }
    }

    #pragma unroll
    for (int a = 0; a < 4; ++a)
        #pragma unroll
        for (int b = 0; b < 4; ++b)
            #pragma unroll
            for (int j = 0; j < 4; ++j) {
                const int row = m0 + wr * 64 + a * 16 + l4 * 4 + j;
                const int col = n0 + wc * 64 + b * 16 + l15;
                const float g = accG[a][b][j];
                const float u = accU[a][b][j];
                const float s = g / (1.0f + __expf(-g));
                hidden[(size_t)row * I_ + col] = f2bf(s * u);
            }
}

// ---------------------------------------------------------------------------
// GEMM2: out[T,H] fp32 = hidden(bf16) @ wdn_bf16^T. Pure global_load_lds staging.
// ---------------------------------------------------------------------------
__global__ __launch_bounds__(256, 2) void k_gemm2(
    const unsigned short* __restrict__ hidden, const unsigned short* __restrict__ wdnb,
    float* __restrict__ out)
{
    __shared__ unsigned short lds[2 * 128 * 64];
    unsigned short* ldsA = lds;              // linear [128][64]
    unsigned short* ldsB = lds + 128 * 64;   // linear

    const int tid  = threadIdx.x;
    const int lane = tid & 63;
    const int wv   = tid >> 6;
    const int wr   = wv >> 1, wc = wv & 1;

    // XCD swizzle over 2048 blocks (2048 % 8 == 0)
    const int nb = (blockIdx.x & 7) * 256 + (blockIdx.x >> 3);
    const int bx = nb % 16, by = nb / 16;
    const int m0 = by * 128;
    const int n0 = bx * 128;

    f32x4 acc[4][4];
    #pragma unroll
    for (int a = 0; a < 4; ++a)
        #pragma unroll
        for (int b = 0; b < 4; ++b) acc[a][b] = (f32x4)0.0f;

    const int drow = lane >> 3;
    const int dcol = (lane & 7) * 8;
    const int l15 = lane & 15;
    const int l4  = lane >> 4;

    for (int k0 = 0; k0 < I_; k0 += 64) {
        __syncthreads();
        #pragma unroll
        for (int r = 0; r < 4; ++r) {
            const int row = r * 32 + wv * 8 + drow;
            const int loff = r * 2048 + wv * 512;
            gload16(hidden + (size_t)(m0 + row) * I_ + k0 + dcol, ldsA + loff);
            gload16(wdnb   + (size_t)(n0 + row) * I_ + k0 + dcol, ldsB + loff);
        }
        __syncthreads();

        #pragma unroll
        for (int kk = 0; kk < 2; ++kk) {
            short8 af[4], bw[4];
            #pragma unroll
            for (int a = 0; a < 4; ++a) {
                const int r = wr * 64 + a * 16 + l15;
                af[a] = *(const short8*)(ldsA + r * 64 + kk * 32 + l4 * 8);
            }
            #pragma unroll
            for (int b = 0; b < 4; ++b) {
                const int r = wc * 64 + b * 16 + l15;
                bw[b] = *(const short8*)(ldsB + r * 64 + kk * 32 + l4 * 8);
            }
            #pragma unroll
            for (int a = 0; a < 4; ++a)
                #pragma unroll
                for (int b = 0; b < 4; ++b)
                    acc[a][b] = __builtin_amdgcn_mfma_f32_16x16x32_bf16(af[a], bw[b], acc[a][b], 0, 0, 0);
        }
    }

    #pragma unroll
    for (int a = 0; a < 4; ++a)
        #pragma unroll
        for (int b = 0; b < 4; ++b)
            #pragma unroll
            for (int j = 0; j < 4; ++j) {
                const int row = m0 + wr * 64 + a * 16 + l4 * 4 + j;
                const int col = n0 + wc * 64 + b * 16 + l15;
                out[(size_t)row * H_ + col] = acc[a][b][j];
            }
}

} // namespace

extern "C" void kernel_launch(void* const* d_in, const int* in_sizes, int n_in,
                              void* d_out, int out_size, void* d_ws, size_t ws_size,
                              hipStream_t stream) {
    const float* x   = (const float*)d_in[0];   // [T, H]
    const float* wgu = (const float*)d_in[1];   // [E, 2I, H]
    const float* wdn = (const float*)d_in[2];   // [E, H, I]
    const int* eidx  = (const int*)d_in[3];     // [1]
    float* out = (float*)d_out;                 // [T, H]

    // ws layout (bytes): hidden[T*I] bf16 @0 (50,331,648)
    //                    wgu_bf16[2I*H]   @50,331,648 (12,582,912)
    //                    wdn_bf16[H*I]    @62,914,560 (6,291,456)   total 69.2 MB
    unsigned short* hidden = (unsigned short*)d_ws;
    unsigned short* wgub   = (unsigned short*)((char*)d_ws + 50331648);
    unsigned short* wdnb   = (unsigned short*)((char*)d_ws + 62914560);

    k_cvt<<<2048, 256, 0, stream>>>(wgu, eidx, (long)(2 * I_) * H_, wgub, (2 * I_ * H_) / 4);
    k_cvt<<<2048, 256, 0, stream>>>(wdn, eidx, (long)H_ * I_, wdnb, (H_ * I_) / 4);
    k_gemm1_swiglu<<<dim3((I_ / 128) * (T_ / 128)), 256, 0, stream>>>(x, wgub, hidden);
    k_gemm2<<<dim3((H_ / 128) * (T_ / 128)), 256, 0, stream>>>(hidden, wdnb, out);
}

// Round 3
// 381.847 us; speedup vs baseline: 2.1973x; 1.0673x over previous
//
#include <hip/hip_runtime.h>
#include <hip/hip_bf16.h>

// Glm4MoeExpertLayers: x[T,H] fp32, Wgu[E,2I,H] fp32, Wdn[E,H,I] fp32, expert_idx
//   gu = x @ Wgu[e]^T ; hidden = silu(gu[:, :I]) * gu[:, I:] ; out = hidden @ Wdn[e]^T
// T=16384 H=2048 I=1536.
// R3: pre-convert x AND weights to bf16 (x-bf16 lives in d_out as scratch);
// both GEMMs are pure global_load_lds(16B) staged, linear LDS, m97 structure.
// GEMM1 keeps dual-B (gate+up share the A tile) + fused SwiGLU epilogue.

namespace {

constexpr int T_ = 16384;
constexpr int H_ = 2048;
constexpr int I_ = 1536;

typedef short short8 __attribute__((ext_vector_type(8)));
typedef float f32x4 __attribute__((ext_vector_type(4)));
typedef unsigned short ushort4v __attribute__((ext_vector_type(4)));

// fp32 -> bf16 round-to-nearest-even
__device__ __forceinline__ unsigned short f2bf(float f) {
    union { float f; unsigned u; } v; v.f = f;
    return (unsigned short)((v.u + 0x7FFFu + ((v.u >> 16) & 1u)) >> 16);
}

// async global->LDS, 16B per lane. LDS dest is wave-uniform base (+lane*16 by HW).
typedef __attribute__((address_space(1))) const void gvoid;
typedef __attribute__((address_space(3))) void lvoid;
__device__ __forceinline__ void gload16(const void* g, void* l) {
    __builtin_amdgcn_global_load_lds((gvoid*)g, (lvoid*)l, 16, 0, 0);
}

// ---------------------------------------------------------------------------
// fp32 -> bf16 conversion. src = base + (*eidx)*sliceElems (sliceElems=0 for x).
// ---------------------------------------------------------------------------
__global__ void k_cvt(const float* __restrict__ base, const int* __restrict__ eidx,
                      long sliceElems, unsigned short* __restrict__ dst, int n4) {
    const float* src = base + (size_t)(*eidx) * (size_t)sliceElems;
    int i = blockIdx.x * blockDim.x + threadIdx.x;
    const int stride = gridDim.x * blockDim.x;
    for (; i < n4; i += stride) {
        f32x4 v = ((const f32x4*)src)[i];
        ushort4v h = { f2bf(v[0]), f2bf(v[1]), f2bf(v[2]), f2bf(v[3]) };
        ((ushort4v*)dst)[i] = h;
    }
}

// ---------------------------------------------------------------------------
// GEMM1 + SwiGLU: hidden[T,I](bf16) = silu(xb@Wg^T) * (xb@Wu^T)
// 256 thr (4 waves 2x2), tile 128x128, BK=64 over H. All operands bf16,
// all staged via global_load_lds into linear [128][64] LDS tiles.
// ---------------------------------------------------------------------------
__global__ __launch_bounds__(256, 2) void k_gemm1_swiglu(
    const unsigned short* __restrict__ xb, const unsigned short* __restrict__ wgub,
    unsigned short* __restrict__ hidden)
{
    __shared__ unsigned short lds[3 * 128 * 64];
    unsigned short* ldsA  = lds;                 // linear [128][64]
    unsigned short* ldsBg = lds + 128 * 64;
    unsigned short* ldsBu = lds + 2 * 128 * 64;

    const int tid  = threadIdx.x;
    const int lane = tid & 63;
    const int wv   = tid >> 6;
    const int wr   = wv >> 1, wc = wv & 1;

    // XCD-aware bijective swizzle over 1536 blocks (1536 % 8 == 0)
    const int nb = (blockIdx.x & 7) * 192 + (blockIdx.x >> 3);
    const int bx = nb % 12, by = nb / 12;
    const int m0 = by * 128;
    const int n0 = bx * 128;

    f32x4 accG[4][4], accU[4][4];
    #pragma unroll
    for (int a = 0; a < 4; ++a)
        #pragma unroll
        for (int b = 0; b < 4; ++b) { accG[a][b] = (f32x4)0.0f; accU[a][b] = (f32x4)0.0f; }

    const int drow = lane >> 3;          // 0..7
    const int dcol = (lane & 7) * 8;     // bf16 elem col
    const int l15 = lane & 15;
    const int l4  = lane >> 4;

    for (int k0 = 0; k0 < H_; k0 += 64) {
        __syncthreads();
        #pragma unroll
        for (int r = 0; r < 4; ++r) {
            const int row  = r * 32 + wv * 8 + drow;
            const int loff = r * 2048 + wv * 512;   // ushort units, wave-uniform
            gload16(xb   + (size_t)(m0 + row)      * H_ + k0 + dcol, ldsA  + loff);
            gload16(wgub + (size_t)(n0 + row)      * H_ + k0 + dcol, ldsBg + loff);
            gload16(wgub + (size_t)(I_ + n0 + row) * H_ + k0 + dcol, ldsBu + loff);
        }
        __syncthreads();

        #pragma unroll
        for (int kk = 0; kk < 2; ++kk) {
            short8 af[4], bg[4], bu[4];
            #pragma unroll
            for (int a = 0; a < 4; ++a) {
                const int r = wr * 64 + a * 16 + l15;
                af[a] = *(const short8*)(ldsA + r * 64 + kk * 32 + l4 * 8);
            }
            #pragma unroll
            for (int b = 0; b < 4; ++b) {
                const int r = wc * 64 + b * 16 + l15;
                bg[b] = *(const short8*)(ldsBg + r * 64 + kk * 32 + l4 * 8);
                bu[b] = *(const short8*)(ldsBu + r * 64 + kk * 32 + l4 * 8);
            }
            #pragma unroll
            for (int a = 0; a < 4; ++a)
                #pragma unroll
                for (int b = 0; b < 4; ++b) {
                    accG[a][b] = __builtin_amdgcn_mfma_f32_16x16x32_bf16(af[a], bg[b], accG[a][b], 0, 0, 0);
                    accU[a][b] = __builtin_amdgcn_mfma_f32_16x16x32_bf16(af[a], bu[b], accU[a][b], 0, 0, 0);
                }
        }
    }

    #pragma unroll
    for (int a = 0; a < 4; ++a)
        #pragma unroll
        for (int b = 0; b < 4; ++b)
            #pragma unroll
            for (int j = 0; j < 4; ++j) {
                const int row = m0 + wr * 64 + a * 16 + l4 * 4 + j;
                const int col = n0 + wc * 64 + b * 16 + l15;
                const float g = accG[a][b][j];
                const float u = accU[a][b][j];
                const float s = g / (1.0f + __expf(-g));
                hidden[(size_t)row * I_ + col] = f2bf(s * u);
            }
}

// ---------------------------------------------------------------------------
// GEMM2: out[T,H] fp32 = hidden(bf16) @ wdn_bf16^T. Pure global_load_lds staging.
// ---------------------------------------------------------------------------
__global__ __launch_bounds__(256, 2) void k_gemm2(
    const unsigned short* __restrict__ hidden, const unsigned short* __restrict__ wdnb,
    float* __restrict__ out)
{
    __shared__ unsigned short lds[2 * 128 * 64];
    unsigned short* ldsA = lds;              // linear [128][64]
    unsigned short* ldsB = lds + 128 * 64;

    const int tid  = threadIdx.x;
    const int lane = tid & 63;
    const int wv   = tid >> 6;
    const int wr   = wv >> 1, wc = wv & 1;

    // XCD swizzle over 2048 blocks (2048 % 8 == 0)
    const int nb = (blockIdx.x & 7) * 256 + (blockIdx.x >> 3);
    const int bx = nb % 16, by = nb / 16;
    const int m0 = by * 128;
    const int n0 = bx * 128;

    f32x4 acc[4][4];
    #pragma unroll
    for (int a = 0; a < 4; ++a)
        #pragma unroll
        for (int b = 0; b < 4; ++b) acc[a][b] = (f32x4)0.0f;

    const int drow = lane >> 3;
    const int dcol = (lane & 7) * 8;
    const int l15 = lane & 15;
    const int l4  = lane >> 4;

    for (int k0 = 0; k0 < I_; k0 += 64) {
        __syncthreads();
        #pragma unroll
        for (int r = 0; r < 4; ++r) {
            const int row  = r * 32 + wv * 8 + drow;
            const int loff = r * 2048 + wv * 512;
            gload16(hidden + (size_t)(m0 + row) * I_ + k0 + dcol, ldsA + loff);
            gload16(wdnb   + (size_t)(n0 + row) * I_ + k0 + dcol, ldsB + loff);
        }
        __syncthreads();

        #pragma unroll
        for (int kk = 0; kk < 2; ++kk) {
            short8 af[4], bw[4];
            #pragma unroll
            for (int a = 0; a < 4; ++a) {
                const int r = wr * 64 + a * 16 + l15;
                af[a] = *(const short8*)(ldsA + r * 64 + kk * 32 + l4 * 8);
            }
            #pragma unroll
            for (int b = 0; b < 4; ++b) {
                const int r = wc * 64 + b * 16 + l15;
                bw[b] = *(const short8*)(ldsB + r * 64 + kk * 32 + l4 * 8);
            }
            #pragma unroll
            for (int a = 0; a < 4; ++a)
                #pragma unroll
                for (int b = 0; b < 4; ++b)
                    acc[a][b] = __builtin_amdgcn_mfma_f32_16x16x32_bf16(af[a], bw[b], acc[a][b], 0, 0, 0);
        }
    }

    #pragma unroll
    for (int a = 0; a < 4; ++a)
        #pragma unroll
        for (int b = 0; b < 4; ++b)
            #pragma unroll
            for (int j = 0; j < 4; ++j) {
                const int row = m0 + wr * 64 + a * 16 + l4 * 4 + j;
                const int col = n0 + wc * 64 + b * 16 + l15;
                out[(size_t)row * H_ + col] = acc[a][b][j];
            }
}

} // namespace

extern "C" void kernel_launch(void* const* d_in, const int* in_sizes, int n_in,
                              void* d_out, int out_size, void* d_ws, size_t ws_size,
                              hipStream_t stream) {
    const float* x   = (const float*)d_in[0];   // [T, H]
    const float* wgu = (const float*)d_in[1];   // [E, 2I, H]
    const float* wdn = (const float*)d_in[2];   // [E, H, I]
    const int* eidx  = (const int*)d_in[3];     // [1]
    float* out = (float*)d_out;                 // [T, H]

    // Scratch plan:
    //   d_out (134.2 MB fp32) temporarily holds xb = bf16(x), 67.1 MB — x is
    //   dead before k_gemm2 overwrites d_out (stream-serialized, deterministic).
    //   d_ws: hidden[T*I] bf16 @0 (50,331,648)
    //         wgu_bf16[2I*H]   @50,331,648 (12,582,912)
    //         wdn_bf16[H*I]    @62,914,560 (6,291,456)   total 69.2 MB (proven fit)
    unsigned short* xb     = (unsigned short*)d_out;
    unsigned short* hidden = (unsigned short*)d_ws;
    unsigned short* wgub   = (unsigned short*)((char*)d_ws + 50331648);
    unsigned short* wdnb   = (unsigned short*)((char*)d_ws + 62914560);

    k_cvt<<<2048, 256, 0, stream>>>(x, eidx, 0L, xb, (T_ * H_) / 4);
    k_cvt<<<2048, 256, 0, stream>>>(wgu, eidx, (long)(2 * I_) * H_, wgub, (2 * I_ * H_) / 4);
    k_cvt<<<2048, 256, 0, stream>>>(wdn, eidx, (long)H_ * I_, wdnb, (H_ * I_) / 4);
    k_gemm1_swiglu<<<dim3((I_ / 128) * (T_ / 128)), 256, 0, stream>>>(xb, wgub, hidden);
    k_gemm2<<<dim3((H_ / 128) * (T_ / 128)), 256, 0, stream>>>(hidden, wdnb, out);
}